// Round 3
// baseline (1614.393 us; speedup 1.0000x reference)
//
#include <hip/hip_runtime.h>

// B=2, S=2048 -> T=4096 tokens, D=1024, F=4096, E=8, top_k on device (always <=E).
// All I/O fp32. Strategy: pre-convert x + transpose-convert W1/W2 to bf16 in ws,
// then m97-style 128x128x32 MFMA GEMMs (all-b128 LDS traffic), fp32 accumulate.
#define T_TOK 4096
#define DIM   1024
#define FDIM  4096
#define NEXP  8

typedef __bf16 bf16x8 __attribute__((ext_vector_type(8)));
typedef float  f32x4  __attribute__((ext_vector_type(4)));

// ---------------------------------------------------------------------------
// Router: one wave per token. fp32 logits; softmax-free top-k (denominator
// cancels under renorm); append (token, weight) to per-expert buckets.
// ---------------------------------------------------------------------------
__global__ __launch_bounds__(64)
void moe_router(const float* __restrict__ x,
                const float* __restrict__ gw,
                const float* __restrict__ gb,
                const int*   __restrict__ topk_p,
                int*   __restrict__ counts,
                int*   __restrict__ bucket,
                float* __restrict__ bweight) {
    const int t = blockIdx.x;
    const int lane = threadIdx.x;
    float part[NEXP];
#pragma unroll
    for (int e = 0; e < NEXP; ++e) part[e] = 0.f;
    const float* xrow = x + (size_t)t * DIM;
    for (int i = lane; i < DIM; i += 64) {
        float xv = xrow[i];
#pragma unroll
        for (int e = 0; e < NEXP; ++e) part[e] += xv * gw[e * DIM + i];
    }
#pragma unroll
    for (int off = 32; off > 0; off >>= 1) {
#pragma unroll
        for (int e = 0; e < NEXP; ++e) part[e] += __shfl_xor(part[e], off);
    }
    if (lane == 0) {
        int k = topk_p[0];
        if (k < 1) k = 1;
        if (k > NEXP) k = NEXP;
        float logit[NEXP];
        float mx = -1e30f;
#pragma unroll
        for (int e = 0; e < NEXP; ++e) {
            logit[e] = part[e] + gb[e];
            mx = fmaxf(mx, logit[e]);
        }
        float p[NEXP];
#pragma unroll
        for (int e = 0; e < NEXP; ++e) p[e] = __expf(logit[e] - mx);
        bool used[NEXP];
#pragma unroll
        for (int e = 0; e < NEXP; ++e) used[e] = false;
        int   sel[NEXP];
        float selp[NEXP];
        float wsum = 0.f;
        for (int j = 0; j < k; ++j) {
            int best = 0; float bv = -1.f;
            for (int e = 0; e < NEXP; ++e)
                if (!used[e] && p[e] > bv) { bv = p[e]; best = e; }  // ties -> low idx
            used[best] = true;
            sel[j] = best; selp[j] = bv; wsum += bv;
        }
        for (int j = 0; j < k; ++j) {
            int e = sel[j];
            int pos = atomicAdd(&counts[e], 1);
            bucket[e * T_TOK + pos]  = t;
            bweight[e * T_TOK + pos] = selp[j] / wsum;
        }
    }
}

__device__ __forceinline__ bf16x8 cvt8(const float* p) {
    float4 v0 = *(const float4*)p;
    float4 v1 = *(const float4*)(p + 4);
    bf16x8 t;
    t[0] = (__bf16)v0.x; t[1] = (__bf16)v0.y; t[2] = (__bf16)v0.z; t[3] = (__bf16)v0.w;
    t[4] = (__bf16)v1.x; t[5] = (__bf16)v1.y; t[6] = (__bf16)v1.z; t[7] = (__bf16)v1.w;
    return t;
}

// Flat fp32 -> bf16 (n multiple of 2048)
__global__ __launch_bounds__(256)
void cvt_bf16(const float* __restrict__ in, __bf16* __restrict__ out) {
    size_t i = ((size_t)blockIdx.x * 256 + threadIdx.x) * 8;
    *(bf16x8*)&out[i] = cvt8(&in[i]);
}

// Per-expert transpose + convert: in [z][R][C] fp32 -> out [z][C][R] bf16.
__global__ __launch_bounds__(256)
void transpose_cvt(const float* __restrict__ in, __bf16* __restrict__ out,
                   int R, int C) {
    const size_t zo = (size_t)blockIdx.z * R * C;
    in  += zo; out += zo;
    __shared__ float ts[32][33];
    const int c0 = blockIdx.x * 32, r0 = blockIdx.y * 32;
    const int lc = threadIdx.x & 31, lr = threadIdx.x >> 5;   // 8 rows per pass
#pragma unroll
    for (int rr = lr; rr < 32; rr += 8)
        ts[rr][lc] = in[(size_t)(r0 + rr) * C + c0 + lc];
    __syncthreads();
#pragma unroll
    for (int cc = lr; cc < 32; cc += 8)
        out[(size_t)(c0 + cc) * R + r0 + lc] = (__bf16)ts[lc][cc];
}

// ---------------------------------------------------------------------------
// GEMM1: H[e,pos,f] = silu( xb[tok] . W1T[e][f][:] + b1[e][f] )   (H bf16)
// 128x128 tile, BK=32, 4 waves (2x2), 4x4 MFMA 16x16x32 per wave.
// ---------------------------------------------------------------------------
__global__ __launch_bounds__(256)
void moe_gemm1(const __bf16* __restrict__ xb,
               const __bf16* __restrict__ w1t,   // [E][F][D]
               const float*  __restrict__ b1,
               const int*    __restrict__ counts,
               const int*    __restrict__ bucket,
               __bf16* __restrict__ H, int Fc, int chunk_f0) {
    const int e    = blockIdx.x >> 5;            // 32 worst-case row tiles
    const int tile = blockIdx.x & 31;
    const int cnt  = counts[e];
    if (tile * 128 >= cnt) return;
    const int nb = blockIdx.y * 128;             // f-tile within chunk

    __shared__ __bf16 As[128][40];
    __shared__ __bf16 Bs[128][40];
    __shared__ int tok_s[128];

    const int tid = threadIdx.x;
    if (tid < 128) {
        int r = tile * 128 + tid;
        if (r >= cnt) r = cnt - 1;               // clamp pad rows (results unused)
        tok_s[tid] = bucket[e * T_TOK + r];
    }
    __syncthreads();

    const int wave = tid >> 6, lane = tid & 63;
    const int wm = wave & 1, wn = wave >> 1;
    const int quad = lane >> 4, l15 = lane & 15;
    const int srow = tid >> 2, skc = (tid & 3) * 8;   // staging: 2 chunks/thread

    f32x4 acc[4][4];
#pragma unroll
    for (int i = 0; i < 4; ++i)
#pragma unroll
        for (int j = 0; j < 4; ++j) acc[i][j] = (f32x4){0.f, 0.f, 0.f, 0.f};

    const __bf16* brow0 = w1t + ((size_t)e * FDIM + chunk_f0 + nb) * DIM;

    for (int k0 = 0; k0 < DIM; k0 += 32) {
        // stage A (gathered token rows) and B (W1T rows), all 16B ops
        bf16x8 a0 = *(const bf16x8*)&xb[(size_t)tok_s[srow]      * DIM + k0 + skc];
        bf16x8 a1 = *(const bf16x8*)&xb[(size_t)tok_s[srow + 64] * DIM + k0 + skc];
        bf16x8 b0 = *(const bf16x8*)&brow0[(size_t)srow        * DIM + k0 + skc];
        bf16x8 b1v = *(const bf16x8*)&brow0[(size_t)(srow + 64) * DIM + k0 + skc];
        *(bf16x8*)&As[srow][skc]      = a0;
        *(bf16x8*)&As[srow + 64][skc] = a1;
        *(bf16x8*)&Bs[srow][skc]      = b0;
        *(bf16x8*)&Bs[srow + 64][skc] = b1v;
        __syncthreads();
        bf16x8 af[4], bf[4];
#pragma unroll
        for (int i = 0; i < 4; ++i)
            af[i] = *(const bf16x8*)&As[wm * 64 + i * 16 + l15][quad * 8];
#pragma unroll
        for (int j = 0; j < 4; ++j)
            bf[j] = *(const bf16x8*)&Bs[wn * 64 + j * 16 + l15][quad * 8];
#pragma unroll
        for (int i = 0; i < 4; ++i)
#pragma unroll
            for (int j = 0; j < 4; ++j)
                acc[i][j] = __builtin_amdgcn_mfma_f32_16x16x32_bf16(
                    af[i], bf[j], acc[i][j], 0, 0, 0);
        __syncthreads();
    }

#pragma unroll
    for (int i = 0; i < 4; ++i)
#pragma unroll
        for (int j = 0; j < 4; ++j)
#pragma unroll
            for (int r = 0; r < 4; ++r) {
                int m = wm * 64 + i * 16 + quad * 4 + r;   // C/D: row=quad*4+reg
                int prow = tile * 128 + m;
                if (prow < cnt) {
                    int fc = nb + wn * 64 + j * 16 + l15;  // C/D: col=lane&15
                    float v = acc[i][j][r] + b1[e * FDIM + chunk_f0 + fc];
                    float s = v / (1.f + __expf(-v));      // silu
                    H[(size_t)(e * T_TOK + prow) * Fc + fc] = (__bf16)s;
                }
            }
}

// ---------------------------------------------------------------------------
// GEMM2: out[tok,d] += weight * ( H[e,pos,:] . W2T[e][d][:] + b2[e][d] )
// ---------------------------------------------------------------------------
__global__ __launch_bounds__(256)
void moe_gemm2(const __bf16* __restrict__ H,
               const __bf16* __restrict__ w2t,   // [E][D][F]
               const float*  __restrict__ b2,
               const int*    __restrict__ counts,
               const int*    __restrict__ bucket,
               const float*  __restrict__ bweight,
               float* __restrict__ out, int Fc, int chunk_f0, int add_bias) {
    const int e    = blockIdx.x >> 5;
    const int tile = blockIdx.x & 31;
    const int cnt  = counts[e];
    if (tile * 128 >= cnt) return;
    const int nb = blockIdx.y * 128;             // d-tile (DIM/128 = 8)

    __shared__ __bf16 As[128][40];
    __shared__ __bf16 Bs[128][40];
    __shared__ int   tok_s[128];
    __shared__ float w_s[128];

    const int tid = threadIdx.x;
    if (tid < 128) {
        int r  = tile * 128 + tid;
        int rc = r < cnt ? r : cnt - 1;
        tok_s[tid] = bucket[e * T_TOK + rc];
        w_s[tid]   = bweight[e * T_TOK + rc];
    }
    __syncthreads();

    const int wave = tid >> 6, lane = tid & 63;
    const int wm = wave & 1, wn = wave >> 1;
    const int quad = lane >> 4, l15 = lane & 15;
    const int srow = tid >> 2, skc = (tid & 3) * 8;

    f32x4 acc[4][4];
#pragma unroll
    for (int i = 0; i < 4; ++i)
#pragma unroll
        for (int j = 0; j < 4; ++j) acc[i][j] = (f32x4){0.f, 0.f, 0.f, 0.f};

    const __bf16* arow0 = H + (size_t)(e * T_TOK + tile * 128) * Fc;
    const __bf16* brow0 = w2t + ((size_t)e * DIM + nb) * FDIM + chunk_f0;

    for (int k0 = 0; k0 < Fc; k0 += 32) {
        bf16x8 a0 = *(const bf16x8*)&arow0[(size_t)srow        * Fc + k0 + skc];
        bf16x8 a1 = *(const bf16x8*)&arow0[(size_t)(srow + 64) * Fc + k0 + skc];
        bf16x8 b0 = *(const bf16x8*)&brow0[(size_t)srow        * FDIM + k0 + skc];
        bf16x8 b1v = *(const bf16x8*)&brow0[(size_t)(srow + 64) * FDIM + k0 + skc];
        *(bf16x8*)&As[srow][skc]      = a0;
        *(bf16x8*)&As[srow + 64][skc] = a1;
        *(bf16x8*)&Bs[srow][skc]      = b0;
        *(bf16x8*)&Bs[srow + 64][skc] = b1v;
        __syncthreads();
        bf16x8 af[4], bf[4];
#pragma unroll
        for (int i = 0; i < 4; ++i)
            af[i] = *(const bf16x8*)&As[wm * 64 + i * 16 + l15][quad * 8];
#pragma unroll
        for (int j = 0; j < 4; ++j)
            bf[j] = *(const bf16x8*)&Bs[wn * 64 + j * 16 + l15][quad * 8];
#pragma unroll
        for (int i = 0; i < 4; ++i)
#pragma unroll
            for (int j = 0; j < 4; ++j)
                acc[i][j] = __builtin_amdgcn_mfma_f32_16x16x32_bf16(
                    af[i], bf[j], acc[i][j], 0, 0, 0);
        __syncthreads();
    }

#pragma unroll
    for (int i = 0; i < 4; ++i)
#pragma unroll
        for (int j = 0; j < 4; ++j)
#pragma unroll
            for (int r = 0; r < 4; ++r) {
                int m = wm * 64 + i * 16 + quad * 4 + r;
                int prow = tile * 128 + m;
                if (prow < cnt) {
                    int dc = nb + wn * 64 + j * 16 + l15;
                    float v = acc[i][j][r];
                    if (add_bias) v += b2[e * DIM + dc];
                    atomicAdd(&out[(size_t)tok_s[m] * DIM + dc], w_s[m] * v);
                }
            }
}

extern "C" void kernel_launch(void* const* d_in, const int* in_sizes, int n_in,
                              void* d_out, int out_size, void* d_ws, size_t ws_size,
                              hipStream_t stream) {
    const float* x  = (const float*)d_in[0];
    const float* gw = (const float*)d_in[1];
    const float* gb = (const float*)d_in[2];
    const float* w1 = (const float*)d_in[3];
    const float* b1 = (const float*)d_in[4];
    const float* w2 = (const float*)d_in[5];
    const float* b2 = (const float*)d_in[6];
    const int* topk = (const int*)d_in[7];
    float* out = (float*)d_out;

    // Workspace layout (0xAA-poisoned every launch; init what we rely on)
    char* ws = (char*)d_ws;
    size_t off = 0;
    int* counts = (int*)(ws + off);     off += 256;
    int* bucket = (int*)(ws + off);     off += (size_t)NEXP * T_TOK * 4;
    float* bw   = (float*)(ws + off);   off += (size_t)NEXP * T_TOK * 4;
    off = (off + 255) & ~(size_t)255;
    __bf16* xb  = (__bf16*)(ws + off);  off += (size_t)T_TOK * DIM * 2;       // 8 MB
    __bf16* w1t = (__bf16*)(ws + off);  off += (size_t)NEXP * DIM * FDIM * 2; // 64 MB
    __bf16* w2t = (__bf16*)(ws + off);  off += (size_t)NEXP * FDIM * DIM * 2; // 64 MB
    __bf16* H   = (__bf16*)(ws + off);
    size_t rem = ws_size > off ? ws_size - off : 0;

    // Largest F-chunk whose H (worst-case full routing) fits in remaining ws.
    int Fc = 128;
    const int cands[6] = {4096, 2048, 1024, 512, 256, 128};
    for (int ci = 0; ci < 6; ++ci)
        if ((size_t)NEXP * T_TOK * cands[ci] * 2 <= rem) { Fc = cands[ci]; break; }

    hipMemsetAsync(out, 0, (size_t)out_size * 4, stream);
    hipMemsetAsync(counts, 0, 256, stream);

    // Pre-pass: bf16 conversion (+ weight transposes so both GEMM operands
    // are k-contiguous => all-b128 LDS traffic in the GEMMs).
    cvt_bf16<<<(T_TOK * DIM) / 2048, 256, 0, stream>>>(x, xb);
    transpose_cvt<<<dim3(FDIM / 32, DIM / 32, NEXP), 256, 0, stream>>>(w1, w1t, DIM, FDIM);
    transpose_cvt<<<dim3(DIM / 32, FDIM / 32, NEXP), 256, 0, stream>>>(w2, w2t, FDIM, DIM);

    moe_router<<<T_TOK, 64, 0, stream>>>(x, gw, gb, topk, counts, bucket, bw);

    const int nchunk = FDIM / Fc;
    for (int c = 0; c < nchunk; ++c) {
        int f0 = c * Fc;
        dim3 g1(NEXP * 32, Fc / 128);
        moe_gemm1<<<g1, 256, 0, stream>>>(xb, w1t, b1, counts, bucket, H, Fc, f0);
        dim3 g2(NEXP * 32, DIM / 128);
        moe_gemm2<<<g2, 256, 0, stream>>>(H, w2t, b2, counts, bucket, bw, out,
                                          Fc, f0, c == 0 ? 1 : 0);
    }
}

// Round 4
// 861.704 us; speedup vs baseline: 1.8735x; 1.8735x over previous
//
#include <hip/hip_runtime.h>

// B=2,S=2048 -> T=4096 tokens, D=1024, F=4096, E=8; top_k on device.
// fp32 I/O; bf16 MFMA compute (fp32 accumulate).
// Structure: router -> work-list -> grouped GEMM1 (glds staging, 128x128) ->
// grouped GEMM2 (glds staging, 64x128, atomics into out).
#define T_TOK 4096
#define DIM   1024
#define FDIM  4096
#define NEXP  8

typedef __bf16 bf16x8 __attribute__((ext_vector_type(8)));
typedef float  f32x4  __attribute__((ext_vector_type(4)));

__device__ __forceinline__ void glds16(const void* g, void* l) {
    __builtin_amdgcn_global_load_lds(
        (const __attribute__((address_space(1))) void*)g,
        (__attribute__((address_space(3))) void*)l, 16, 0, 0);
}

// ---------------------------------------------------------------------------
// Router: one wave per token; softmax-free top-k (denominator cancels).
// ---------------------------------------------------------------------------
__global__ __launch_bounds__(64)
void moe_router(const float* __restrict__ x,
                const float* __restrict__ gw,
                const float* __restrict__ gb,
                const int*   __restrict__ topk_p,
                int*   __restrict__ counts,
                int*   __restrict__ bucket,
                float* __restrict__ bweight) {
    const int t = blockIdx.x;
    const int lane = threadIdx.x;
    float part[NEXP];
#pragma unroll
    for (int e = 0; e < NEXP; ++e) part[e] = 0.f;
    const float* xrow = x + (size_t)t * DIM;
    for (int i = lane; i < DIM; i += 64) {
        float xv = xrow[i];
#pragma unroll
        for (int e = 0; e < NEXP; ++e) part[e] += xv * gw[e * DIM + i];
    }
#pragma unroll
    for (int off = 32; off > 0; off >>= 1) {
#pragma unroll
        for (int e = 0; e < NEXP; ++e) part[e] += __shfl_xor(part[e], off);
    }
    if (lane == 0) {
        int k = topk_p[0];
        if (k < 1) k = 1;
        if (k > NEXP) k = NEXP;
        float logit[NEXP];
        float mx = -1e30f;
#pragma unroll
        for (int e = 0; e < NEXP; ++e) {
            logit[e] = part[e] + gb[e];
            mx = fmaxf(mx, logit[e]);
        }
        float p[NEXP];
#pragma unroll
        for (int e = 0; e < NEXP; ++e) p[e] = __expf(logit[e] - mx);
        bool used[NEXP];
#pragma unroll
        for (int e = 0; e < NEXP; ++e) used[e] = false;
        int sel[NEXP]; float selp[NEXP]; float wsum = 0.f;
        for (int j = 0; j < k; ++j) {
            int best = 0; float bv = -1.f;
            for (int e = 0; e < NEXP; ++e)
                if (!used[e] && p[e] > bv) { bv = p[e]; best = e; }  // ties->low idx
            used[best] = true; sel[j] = best; selp[j] = bv; wsum += bv;
        }
        for (int j = 0; j < k; ++j) {
            int e = sel[j];
            int pos = atomicAdd(&counts[e], 1);
            bucket[e * T_TOK + pos]  = t;
            bweight[e * T_TOK + pos] = selp[j] / wsum;
        }
    }
}

// Flat fp32 -> bf16
__global__ __launch_bounds__(256)
void cvt_bf16(const float* __restrict__ in, __bf16* __restrict__ out) {
    size_t i = ((size_t)blockIdx.x * 256 + threadIdx.x) * 8;
    float4 v0 = *(const float4*)&in[i];
    float4 v1 = *(const float4*)&in[i + 4];
    bf16x8 t;
    t[0]=(__bf16)v0.x; t[1]=(__bf16)v0.y; t[2]=(__bf16)v0.z; t[3]=(__bf16)v0.w;
    t[4]=(__bf16)v1.x; t[5]=(__bf16)v1.y; t[6]=(__bf16)v1.z; t[7]=(__bf16)v1.w;
    *(bf16x8*)&out[i] = t;
}

// Per-expert transpose+convert: in [z][R][C] fp32 -> out [z][C][R] bf16.
// 64x64 tiles; b128 bf16 stores (full-line coalescing).
__global__ __launch_bounds__(256)
void transpose_cvt(const float* __restrict__ in, __bf16* __restrict__ out,
                   int R, int C) {
    const size_t zo = (size_t)blockIdx.z * R * C;
    in += zo; out += zo;
    __shared__ float ts[64][65];
    const int c0 = blockIdx.x * 64, r0 = blockIdx.y * 64;
    const int t = threadIdx.x;
    const int rr = t >> 2, cc4 = (t & 3) * 16;
    const float* src = in + (size_t)(r0 + rr) * C + c0 + cc4;
#pragma unroll
    for (int i = 0; i < 4; ++i) {
        float4 v = *(const float4*)(src + i * 4);
        ts[rr][cc4 + i*4 + 0] = v.x; ts[rr][cc4 + i*4 + 1] = v.y;
        ts[rr][cc4 + i*4 + 2] = v.z; ts[rr][cc4 + i*4 + 3] = v.w;
    }
    __syncthreads();
    const int oc = rr, orc = cc4;           // out col-in-tile, row-chunk
    bf16x8 o0, o1;
#pragma unroll
    for (int i = 0; i < 8; ++i) o0[i] = (__bf16)ts[orc + i][oc];
#pragma unroll
    for (int i = 0; i < 8; ++i) o1[i] = (__bf16)ts[orc + 8 + i][oc];
    __bf16* dst = out + (size_t)(c0 + oc) * R + r0 + orc;
    *(bf16x8*)dst = o0;
    *(bf16x8*)(dst + 8) = o1;
}

// ---------------------------------------------------------------------------
// Work-list: entries1 = (e,tile128) for GEMM1, entries2 = (e,tile64) for GEMM2.
// hdr[0]=n1, hdr[1]=n2, entries1 at hdr+8 (<=256), entries2 at hdr+264 (<=512).
// ---------------------------------------------------------------------------
__global__ __launch_bounds__(64)
void build_work(const int* __restrict__ counts, int* __restrict__ hdr) {
    __shared__ int off1[NEXP + 1], off2[NEXP + 1];
    const int lane = threadIdx.x;
    if (lane == 0) {
        int a = 0, b = 0;
        for (int e = 0; e < NEXP; ++e) {
            off1[e] = a; off2[e] = b;
            a += (counts[e] + 127) >> 7;
            b += (counts[e] + 63) >> 6;
        }
        off1[NEXP] = a; off2[NEXP] = b;
        hdr[0] = a; hdr[1] = b;
    }
    __syncthreads();
    for (int e = 0; e < NEXP; ++e) {
        int n1 = off1[e + 1] - off1[e];
        for (int j = lane; j < n1; j += 64) hdr[8 + off1[e] + j] = (e << 16) | j;
        int n2 = off2[e + 1] - off2[e];
        for (int j = lane; j < n2; j += 64) hdr[264 + off2[e] + j] = (e << 16) | j;
    }
}

// ---------------------------------------------------------------------------
// GEMM1: H[e,pos,f] = silu( xb[tok].W1T[e][f][:] + b1[e][f] )
// Persistent blocks over (tile128 x f-tile128) units. glds staging, BK=32.
// ---------------------------------------------------------------------------
__global__ __launch_bounds__(256)
void moe_gemm1(const __bf16* __restrict__ xb,
               const __bf16* __restrict__ w1t,   // [E][F][D]
               const float*  __restrict__ b1,
               const int*    __restrict__ counts,
               const int*    __restrict__ bucket,
               const int*    __restrict__ hdr,
               __bf16* __restrict__ H) {
    __shared__ __bf16 smem[8192];                // As=smem[0..4095], Bs=[4096..]
    __shared__ int tok_s[128];
    const int tid = threadIdx.x;
    const int wave = tid >> 6, lane = tid & 63;
    const int wm = wave & 1, wn = wave >> 1;
    const int quad = lane >> 4, l15 = lane & 15;
    const int srow = tid >> 2, skc = (tid & 3) * 8;
    char* lA = (char*)smem + (size_t)wave * 1024;
    char* lB = (char*)smem + 8192 + (size_t)wave * 1024;

    const int n1 = hdr[0];
    const int total = n1 * (FDIM / 128);
    for (int u = blockIdx.x; u < total; u += gridDim.x) {
        const int entry = hdr[8 + (u % n1)];
        const int e = entry >> 16, tile = entry & 0xffff;
        const int nb = (u / n1) * 128;
        const int cnt = counts[e];
        if (tid < 128) {
            int r = tile * 128 + tid;
            if (r >= cnt) r = cnt - 1;
            tok_s[tid] = bucket[e * T_TOK + r];
        }
        __syncthreads();

        const __bf16* pa0 = xb + (size_t)tok_s[srow]      * DIM + skc;
        const __bf16* pa1 = xb + (size_t)tok_s[srow + 64] * DIM + skc;
        const __bf16* pb0 = w1t + ((size_t)e * FDIM + nb + srow) * DIM + skc;
        const __bf16* pb1 = pb0 + (size_t)64 * DIM;

        f32x4 acc[4][4];
#pragma unroll
        for (int i = 0; i < 4; ++i)
#pragma unroll
            for (int j = 0; j < 4; ++j) acc[i][j] = (f32x4){0.f,0.f,0.f,0.f};

        for (int k0 = 0; k0 < DIM; k0 += 32) {
            glds16(pa0 + k0, lA);
            glds16(pa1 + k0, lA + 4096);
            glds16(pb0 + k0, lB);
            glds16(pb1 + k0, lB + 4096);
            __syncthreads();
            bf16x8 af[4], bfr[4];
#pragma unroll
            for (int i = 0; i < 4; ++i)
                af[i] = *(const bf16x8*)&smem[(wm*64 + i*16 + l15)*32 + quad*8];
#pragma unroll
            for (int j = 0; j < 4; ++j)
                bfr[j] = *(const bf16x8*)&smem[4096 + (wn*64 + j*16 + l15)*32 + quad*8];
#pragma unroll
            for (int i = 0; i < 4; ++i)
#pragma unroll
                for (int j = 0; j < 4; ++j)
                    acc[i][j] = __builtin_amdgcn_mfma_f32_16x16x32_bf16(
                        af[i], bfr[j], acc[i][j], 0, 0, 0);
            __syncthreads();
        }

        // Epilogue: per-wave C transpose through LDS (stride 68, conflict-free)
        // -> b128 H stores. Wave region: 2048 elements of smem.
        __bf16* stg = smem + wave * 2048;
        const float* b1e = b1 + e * FDIM + nb + wn * 64;
#pragma unroll
        for (int i = 0; i < 4; ++i) {
#pragma unroll
            for (int j = 0; j < 4; ++j) {
                float bias = b1e[j * 16 + l15];
#pragma unroll
                for (int r = 0; r < 4; ++r) {
                    float v = acc[i][j][r] + bias;
                    float s = v / (1.f + __expf(-v));   // silu
                    stg[(quad*4 + r) * 68 + j*16 + l15] = (__bf16)s;
                }
            }
            __syncthreads();
            int rr = lane >> 2, coff = (lane & 3) * 16;
            int prow = tile * 128 + wm * 64 + i * 16 + rr;
            if (prow < cnt) {
                bf16x8 v0 = *(const bf16x8*)&stg[rr * 68 + coff];
                bf16x8 v1 = *(const bf16x8*)&stg[rr * 68 + coff + 8];
                __bf16* dst = H + (size_t)(e * T_TOK + prow) * FDIM
                              + nb + wn * 64 + coff;
                *(bf16x8*)dst = v0;
                *(bf16x8*)(dst + 8) = v1;
            }
            __syncthreads();
        }
    }
}

// ---------------------------------------------------------------------------
// GEMM2: out[tok,d] += w * ( H[e,pos,:].W2T[e][d][:] + b2[e][d] )
// 64x128 tiles, K=FDIM, glds staging, fp32 atomics into out.
// ---------------------------------------------------------------------------
__global__ __launch_bounds__(256)
void moe_gemm2(const __bf16* __restrict__ H,
               const __bf16* __restrict__ w2t,   // [E][D][F]
               const float*  __restrict__ b2,
               const int*    __restrict__ counts,
               const int*    __restrict__ bucket,
               const float*  __restrict__ bweight,
               const int*    __restrict__ hdr,
               float* __restrict__ out) {
    __shared__ __bf16 smem[6144];                // As=[0..2047], Bs=[2048..6143]
    __shared__ int   tok_s[64];
    __shared__ float w_s[64];
    const int tid = threadIdx.x;
    const int wave = tid >> 6, lane = tid & 63;
    const int wm = wave & 1, wn = wave >> 1;
    const int quad = lane >> 4, l15 = lane & 15;
    const int srow = tid >> 2, skc = (tid & 3) * 8;
    char* lA = (char*)smem + (size_t)wave * 1024;          // 4KB total
    char* lB = (char*)smem + 4096 + (size_t)wave * 1024;   // 8KB total

    const int n2 = hdr[1];
    const int total = n2 * (DIM / 128);
    for (int u = blockIdx.x; u < total; u += gridDim.x) {
        const int entry = hdr[264 + (u % n2)];
        const int e = entry >> 16, tile = entry & 0xffff;
        const int nb = (u / n2) * 128;
        const int cnt = counts[e];
        if (tid < 64) {
            int r = tile * 64 + tid;
            int rc = r < cnt ? r : cnt - 1;
            tok_s[tid] = bucket[e * T_TOK + rc];
            w_s[tid]   = bweight[e * T_TOK + rc];
        }
        __syncthreads();

        const __bf16* pa  = H + (size_t)(e * T_TOK + tile * 64 + srow) * FDIM + skc;
        const __bf16* pb0 = w2t + ((size_t)e * DIM + nb + srow) * FDIM + skc;
        const __bf16* pb1 = pb0 + (size_t)64 * FDIM;

        f32x4 acc[2][4];
#pragma unroll
        for (int i = 0; i < 2; ++i)
#pragma unroll
            for (int j = 0; j < 4; ++j) acc[i][j] = (f32x4){0.f,0.f,0.f,0.f};

        for (int k0 = 0; k0 < FDIM; k0 += 32) {
            glds16(pa  + k0, lA);
            glds16(pb0 + k0, lB);
            glds16(pb1 + k0, lB + 4096);
            __syncthreads();
            bf16x8 af[2], bfr[4];
#pragma unroll
            for (int i = 0; i < 2; ++i)
                af[i] = *(const bf16x8*)&smem[(wm*32 + i*16 + l15)*32 + quad*8];
#pragma unroll
            for (int j = 0; j < 4; ++j)
                bfr[j] = *(const bf16x8*)&smem[2048 + (wn*64 + j*16 + l15)*32 + quad*8];
#pragma unroll
            for (int i = 0; i < 2; ++i)
#pragma unroll
                for (int j = 0; j < 4; ++j)
                    acc[i][j] = __builtin_amdgcn_mfma_f32_16x16x32_bf16(
                        af[i], bfr[j], acc[i][j], 0, 0, 0);
            __syncthreads();
        }

#pragma unroll
        for (int i = 0; i < 2; ++i)
#pragma unroll
            for (int j = 0; j < 4; ++j)
#pragma unroll
                for (int r = 0; r < 4; ++r) {
                    int m = wm*32 + i*16 + quad*4 + r;
                    int prow = tile * 64 + m;
                    if (prow < cnt) {
                        int dc = nb + wn*64 + j*16 + l15;
                        float v = acc[i][j][r] + b2[e * DIM + dc];
                        atomicAdd(&out[(size_t)tok_s[m] * DIM + dc], w_s[m] * v);
                    }
                }
        __syncthreads();
    }
}

extern "C" void kernel_launch(void* const* d_in, const int* in_sizes, int n_in,
                              void* d_out, int out_size, void* d_ws, size_t ws_size,
                              hipStream_t stream) {
    const float* x  = (const float*)d_in[0];
    const float* gw = (const float*)d_in[1];
    const float* gb = (const float*)d_in[2];
    const float* w1 = (const float*)d_in[3];
    const float* b1 = (const float*)d_in[4];
    const float* w2 = (const float*)d_in[5];
    const float* b2 = (const float*)d_in[6];
    const int* topk = (const int*)d_in[7];
    float* out = (float*)d_out;

    // ws layout (poisoned 0xAA each launch)
    char* ws = (char*)d_ws;
    size_t off = 0;
    int* counts = (int*)(ws + off);    off += 256;
    int* bucket = (int*)(ws + off);    off += (size_t)NEXP * T_TOK * 4;
    float* bw   = (float*)(ws + off);  off += (size_t)NEXP * T_TOK * 4;
    int* hdr    = (int*)(ws + off);    off += 4096;
    off = (off + 255) & ~(size_t)255;
    __bf16* xb  = (__bf16*)(ws + off); off += (size_t)T_TOK * DIM * 2;        // 8MB
    __bf16* w1t = (__bf16*)(ws + off); off += (size_t)NEXP * DIM * FDIM * 2;  // 64MB
    __bf16* w2t = (__bf16*)(ws + off); off += (size_t)NEXP * FDIM * DIM * 2;  // 64MB
    __bf16* H   = (__bf16*)(ws + off);                                        // 256MB

    hipMemsetAsync(counts, 0, 256, stream);
    hipMemsetAsync(out, 0, (size_t)out_size * 4, stream);

    moe_router<<<T_TOK, 64, 0, stream>>>(x, gw, gb, topk, counts, bucket, bw);
    cvt_bf16<<<(T_TOK * DIM) / 2048, 256, 0, stream>>>(x, xb);
    transpose_cvt<<<dim3(FDIM/64, DIM/64, NEXP), 256, 0, stream>>>(w1, w1t, DIM, FDIM);
    transpose_cvt<<<dim3(DIM/64, FDIM/64, NEXP), 256, 0, stream>>>(w2, w2t, FDIM, DIM);
    build_work<<<1, 64, 0, stream>>>(counts, hdr);

    moe_gemm1<<<1024, 256, 0, stream>>>(xb, w1t, b1, counts, bucket, hdr, H);
    moe_gemm2<<<1024, 256, 0, stream>>>(H, w2t, b2, counts, bucket, bw, hdr, out);
}

// Round 5
// 824.780 us; speedup vs baseline: 1.9574x; 1.0448x over previous
//
#include <hip/hip_runtime.h>

// B=2,S=2048 -> T=4096 tokens, D=1024, F=4096, E=8; top_k on device.
// fp32 I/O; bf16 MFMA compute (fp32 accumulate).
// R5: BK=64 (two [128][32] sub-tiles), 128x128 tiles in BOTH gemms,
// barrier-free gemm1 epilogue, router fused with x->bf16 convert.
#define T_TOK 4096
#define DIM   1024
#define FDIM  4096
#define NEXP  8

typedef __bf16 bf16x8 __attribute__((ext_vector_type(8)));
typedef __bf16 bf16x4 __attribute__((ext_vector_type(4)));
typedef float  f32x4  __attribute__((ext_vector_type(4)));

__device__ __forceinline__ void glds16(const void* g, void* l) {
    __builtin_amdgcn_global_load_lds(
        (const __attribute__((address_space(1))) void*)g,
        (__attribute__((address_space(3))) void*)l, 16, 0, 0);
}

// ---------------------------------------------------------------------------
// Router (+ x->bf16 convert): one wave per token.
// ---------------------------------------------------------------------------
__global__ __launch_bounds__(64)
void moe_router(const float* __restrict__ x,
                const float* __restrict__ gw,
                const float* __restrict__ gb,
                const int*   __restrict__ topk_p,
                int*   __restrict__ counts,
                int*   __restrict__ bucket,
                float* __restrict__ bweight,
                __bf16* __restrict__ xb) {
    const int t = blockIdx.x;
    const int lane = threadIdx.x;
    float part[NEXP];
#pragma unroll
    for (int e = 0; e < NEXP; ++e) part[e] = 0.f;
    const float* xrow = x + (size_t)t * DIM;
    __bf16* xbrow = xb + (size_t)t * DIM;
#pragma unroll
    for (int r = 0; r < 4; ++r) {
        int c = r * 256 + lane * 4;
        float4 v = *(const float4*)&xrow[c];
        bf16x4 o; o[0]=(__bf16)v.x; o[1]=(__bf16)v.y; o[2]=(__bf16)v.z; o[3]=(__bf16)v.w;
        *(bf16x4*)&xbrow[c] = o;
#pragma unroll
        for (int e = 0; e < NEXP; ++e) {
            float4 g = *(const float4*)&gw[e * DIM + c];
            part[e] += v.x*g.x + v.y*g.y + v.z*g.z + v.w*g.w;
        }
    }
#pragma unroll
    for (int off = 32; off > 0; off >>= 1) {
#pragma unroll
        for (int e = 0; e < NEXP; ++e) part[e] += __shfl_xor(part[e], off);
    }
    if (lane == 0) {
        int k = topk_p[0];
        if (k < 1) k = 1;
        if (k > NEXP) k = NEXP;
        float p[NEXP];
        float mx = -1e30f;
#pragma unroll
        for (int e = 0; e < NEXP; ++e) {
            p[e] = part[e] + gb[e];
            mx = fmaxf(mx, p[e]);
        }
#pragma unroll
        for (int e = 0; e < NEXP; ++e) p[e] = __expf(p[e] - mx);
        bool used[NEXP];
#pragma unroll
        for (int e = 0; e < NEXP; ++e) used[e] = false;
        int sel[NEXP]; float selp[NEXP]; float wsum = 0.f;
        for (int j = 0; j < k; ++j) {
            int best = 0; float bv = -1.f;
            for (int e = 0; e < NEXP; ++e)
                if (!used[e] && p[e] > bv) { bv = p[e]; best = e; }  // ties->low idx
            used[best] = true; sel[j] = best; selp[j] = bv; wsum += bv;
        }
        for (int j = 0; j < k; ++j) {
            int e = sel[j];
            int pos = atomicAdd(&counts[e], 1);
            bucket[e * T_TOK + pos]  = t;
            bweight[e * T_TOK + pos] = selp[j] / wsum;
        }
    }
}

// Per-expert transpose+convert: in [z][R][C] fp32 -> out [z][C][R] bf16.
__global__ __launch_bounds__(256)
void transpose_cvt(const float* __restrict__ in, __bf16* __restrict__ out,
                   int R, int C) {
    const size_t zo = (size_t)blockIdx.z * R * C;
    in += zo; out += zo;
    __shared__ float ts[64][65];
    const int c0 = blockIdx.x * 64, r0 = blockIdx.y * 64;
    const int t = threadIdx.x;
    const int rr = t >> 2, cc4 = (t & 3) * 16;
    const float* src = in + (size_t)(r0 + rr) * C + c0 + cc4;
#pragma unroll
    for (int i = 0; i < 4; ++i) {
        float4 v = *(const float4*)(src + i * 4);
        ts[rr][cc4 + i*4 + 0] = v.x; ts[rr][cc4 + i*4 + 1] = v.y;
        ts[rr][cc4 + i*4 + 2] = v.z; ts[rr][cc4 + i*4 + 3] = v.w;
    }
    __syncthreads();
    const int oc = rr, orc = cc4;
    bf16x8 o0, o1;
#pragma unroll
    for (int i = 0; i < 8; ++i) o0[i] = (__bf16)ts[orc + i][oc];
#pragma unroll
    for (int i = 0; i < 8; ++i) o1[i] = (__bf16)ts[orc + 8 + i][oc];
    __bf16* dst = out + (size_t)(c0 + oc) * R + r0 + orc;
    *(bf16x8*)dst = o0;
    *(bf16x8*)(dst + 8) = o1;
}

// ---------------------------------------------------------------------------
// Work list: one list of (e, tile128) entries; hdr[0]=n, entries at hdr+8.
// ---------------------------------------------------------------------------
__global__ __launch_bounds__(64)
void build_work(const int* __restrict__ counts, int* __restrict__ hdr) {
    __shared__ int off1[NEXP + 1];
    const int lane = threadIdx.x;
    if (lane == 0) {
        int a = 0;
        for (int e = 0; e < NEXP; ++e) {
            off1[e] = a;
            a += (counts[e] + 127) >> 7;
        }
        off1[NEXP] = a;
        hdr[0] = a;
    }
    __syncthreads();
    for (int e = 0; e < NEXP; ++e) {
        int n1 = off1[e + 1] - off1[e];
        for (int j = lane; j < n1; j += 64) hdr[8 + off1[e] + j] = (e << 16) | j;
    }
}

// Shared tile geometry: A/B each 2 sub-tiles [128 rows][32 elems] (64 B rows).
//   A sub-tile kk at elem offset kk*4096;  B at 8192 + kk*4096.

// ---------------------------------------------------------------------------
// GEMM1: H[e,pos,f] = silu( xb[tok].W1T[e][f][:] + b1[e][f] )   128x128, BK=64
// ---------------------------------------------------------------------------
__global__ __launch_bounds__(256, 3)
void moe_gemm1(const __bf16* __restrict__ xb,
               const __bf16* __restrict__ w1t,   // [E][F][D]
               const float*  __restrict__ b1,
               const int*    __restrict__ counts,
               const int*    __restrict__ bucket,
               const int*    __restrict__ hdr,
               __bf16* __restrict__ H) {
    __shared__ __bf16 smem[16384];               // 32 KB
    __shared__ int tok_s[128];
    const int tid = threadIdx.x;
    const int wave = tid >> 6, lane = tid & 63;
    const int wm = wave & 1, wn = wave >> 1;
    const int quad = lane >> 4, l15 = lane & 15;
    const int lrow = lane >> 2;                  // 0..15: row within 16-row group
    const int lk8  = (lane & 3) * 8;             // elem offset within 64-elem row
    char* sb = (char*)smem;
    char* dA0 = sb + wave * 2048;                // kk=0, rows wave*32..+15
    char* dA1 = sb + 8192 + wave * 2048;         // kk=1
    char* dB0 = sb + 16384 + wave * 2048;
    char* dB1 = sb + 24576 + wave * 2048;

    const int n1 = hdr[0];
    const int total = n1 * (FDIM / 128);
    for (int u = blockIdx.x; u < total; u += gridDim.x) {
        const int entry = hdr[8 + (u % n1)];
        const int e = entry >> 16, tile = entry & 0xffff;
        const int nb = (u / n1) * 128;
        const int cnt = counts[e];
        if (tid < 128) {
            int r = tile * 128 + tid;
            if (r >= cnt) r = cnt - 1;
            tok_s[tid] = bucket[e * T_TOK + r];
        }
        __syncthreads();

        const int ar0 = wave * 32 + lrow;
        const __bf16* pA0 = xb + (size_t)tok_s[ar0]      * DIM + lk8;
        const __bf16* pA1 = xb + (size_t)tok_s[ar0 + 16] * DIM + lk8;
        const __bf16* pB0 = w1t + ((size_t)e * FDIM + nb + wave * 32 + lrow) * DIM + lk8;
        const __bf16* pB1 = pB0 + (size_t)16 * DIM;

        f32x4 acc[4][4];
#pragma unroll
        for (int i = 0; i < 4; ++i)
#pragma unroll
            for (int j = 0; j < 4; ++j) acc[i][j] = (f32x4){0.f,0.f,0.f,0.f};

        for (int k0 = 0; k0 < DIM; k0 += 64) {
            glds16(pA0 + k0,      dA0);
            glds16(pA0 + k0 + 32, dA1);
            glds16(pA1 + k0,      dA0 + 1024);
            glds16(pA1 + k0 + 32, dA1 + 1024);
            glds16(pB0 + k0,      dB0);
            glds16(pB0 + k0 + 32, dB1);
            glds16(pB1 + k0,      dB0 + 1024);
            glds16(pB1 + k0 + 32, dB1 + 1024);
            __syncthreads();
#pragma unroll
            for (int kk = 0; kk < 2; ++kk) {
                bf16x8 af[4], bfr[4];
#pragma unroll
                for (int i = 0; i < 4; ++i)
                    af[i] = *(const bf16x8*)&smem[kk*4096 + (wm*64 + i*16 + l15)*32 + quad*8];
#pragma unroll
                for (int j = 0; j < 4; ++j)
                    bfr[j] = *(const bf16x8*)&smem[8192 + kk*4096 + (wn*64 + j*16 + l15)*32 + quad*8];
#pragma unroll
                for (int i = 0; i < 4; ++i)
#pragma unroll
                    for (int j = 0; j < 4; ++j)
                        acc[i][j] = __builtin_amdgcn_mfma_f32_16x16x32_bf16(
                            af[i], bfr[j], acc[i][j], 0, 0, 0);
            }
            __syncthreads();
        }

        // Epilogue: wave-private LDS transpose (stride 72 elems, 16B-aligned)
        // -> b128 H stores. No block barriers inside.
        __bf16* stg = (__bf16*)(sb + wave * 2304);
        const float* b1e = b1 + e * FDIM + nb + wn * 64;
#pragma unroll
        for (int i = 0; i < 4; ++i) {
#pragma unroll
            for (int j = 0; j < 4; ++j) {
                float bias = b1e[j * 16 + l15];
#pragma unroll
                for (int r = 0; r < 4; ++r) {
                    float v = acc[i][j][r] + bias;
                    float s = v / (1.f + __expf(-v));   // silu
                    stg[(quad*4 + r) * 72 + j*16 + l15] = (__bf16)s;
                }
            }
            int prow = tile * 128 + wm * 64 + i * 16 + lrow;
            if (prow < cnt) {
                bf16x8 v0 = *(const bf16x8*)&stg[lrow * 72 + (lane & 3) * 16];
                bf16x8 v1 = *(const bf16x8*)&stg[lrow * 72 + (lane & 3) * 16 + 8];
                __bf16* dst = H + (size_t)(e * T_TOK + prow) * FDIM
                              + nb + wn * 64 + (lane & 3) * 16;
                *(bf16x8*)dst = v0;
                *(bf16x8*)(dst + 8) = v1;
            }
        }
        __syncthreads();   // protect smem/tok_s before next unit
    }
}

// ---------------------------------------------------------------------------
// GEMM2: out[tok,d] += w * ( H[e,pos,:].W2T[e][d][:] + b2[e][d] )  128x128, BK=64
// ---------------------------------------------------------------------------
__global__ __launch_bounds__(256, 3)
void moe_gemm2(const __bf16* __restrict__ H,
               const __bf16* __restrict__ w2t,   // [E][D][F]
               const float*  __restrict__ b2,
               const int*    __restrict__ counts,
               const int*    __restrict__ bucket,
               const float*  __restrict__ bweight,
               const int*    __restrict__ hdr,
               float* __restrict__ out) {
    __shared__ __bf16 smem[16384];
    __shared__ int   tok_s[128];
    __shared__ float w_s[128];
    const int tid = threadIdx.x;
    const int wave = tid >> 6, lane = tid & 63;
    const int wm = wave & 1, wn = wave >> 1;
    const int quad = lane >> 4, l15 = lane & 15;
    const int lrow = lane >> 2;
    const int lk8  = (lane & 3) * 8;
    char* sb = (char*)smem;
    char* dA0 = sb + wave * 2048;
    char* dA1 = sb + 8192 + wave * 2048;
    char* dB0 = sb + 16384 + wave * 2048;
    char* dB1 = sb + 24576 + wave * 2048;

    const int n1 = hdr[0];
    const int total = n1 * (DIM / 128);
    for (int u = blockIdx.x; u < total; u += gridDim.x) {
        const int entry = hdr[8 + (u % n1)];
        const int e = entry >> 16, tile = entry & 0xffff;
        const int nb = (u / n1) * 128;
        const int cnt = counts[e];
        if (tid < 128) {
            int r  = tile * 128 + tid;
            int rc = r < cnt ? r : cnt - 1;
            tok_s[tid] = bucket[e * T_TOK + rc];
            w_s[tid]   = bweight[e * T_TOK + rc];
        }
        __syncthreads();

        // A rows (H) are contiguous positions — no gather needed.
        const __bf16* pA0 = H + (size_t)(e * T_TOK + tile * 128 + wave * 32 + lrow) * FDIM + lk8;
        const __bf16* pA1 = pA0 + (size_t)16 * FDIM;
        const __bf16* pB0 = w2t + ((size_t)e * DIM + nb + wave * 32 + lrow) * FDIM + lk8;
        const __bf16* pB1 = pB0 + (size_t)16 * FDIM;

        f32x4 acc[4][4];
#pragma unroll
        for (int i = 0; i < 4; ++i)
#pragma unroll
            for (int j = 0; j < 4; ++j) acc[i][j] = (f32x4){0.f,0.f,0.f,0.f};

        for (int k0 = 0; k0 < FDIM; k0 += 64) {
            glds16(pA0 + k0,      dA0);
            glds16(pA0 + k0 + 32, dA1);
            glds16(pA1 + k0,      dA0 + 1024);
            glds16(pA1 + k0 + 32, dA1 + 1024);
            glds16(pB0 + k0,      dB0);
            glds16(pB0 + k0 + 32, dB1);
            glds16(pB1 + k0,      dB0 + 1024);
            glds16(pB1 + k0 + 32, dB1 + 1024);
            __syncthreads();
#pragma unroll
            for (int kk = 0; kk < 2; ++kk) {
                bf16x8 af[4], bfr[4];
#pragma unroll
                for (int i = 0; i < 4; ++i)
                    af[i] = *(const bf16x8*)&smem[kk*4096 + (wm*64 + i*16 + l15)*32 + quad*8];
#pragma unroll
                for (int j = 0; j < 4; ++j)
                    bfr[j] = *(const bf16x8*)&smem[8192 + kk*4096 + (wn*64 + j*16 + l15)*32 + quad*8];
#pragma unroll
                for (int i = 0; i < 4; ++i)
#pragma unroll
                    for (int j = 0; j < 4; ++j)
                        acc[i][j] = __builtin_amdgcn_mfma_f32_16x16x32_bf16(
                            af[i], bfr[j], acc[i][j], 0, 0, 0);
            }
            __syncthreads();
        }

#pragma unroll
        for (int i = 0; i < 4; ++i)
#pragma unroll
            for (int j = 0; j < 4; ++j)
#pragma unroll
                for (int r = 0; r < 4; ++r) {
                    int m = wm*64 + i*16 + quad*4 + r;
                    int prow = tile * 128 + m;
                    if (prow < cnt) {
                        int dc = nb + wn*64 + j*16 + l15;
                        float v = acc[i][j][r] + b2[e * DIM + dc];
                        atomicAdd(&out[(size_t)tok_s[m] * DIM + dc], w_s[m] * v);
                    }
                }
        __syncthreads();   // protect tok_s/w_s before next unit
    }
}

extern "C" void kernel_launch(void* const* d_in, const int* in_sizes, int n_in,
                              void* d_out, int out_size, void* d_ws, size_t ws_size,
                              hipStream_t stream) {
    const float* x  = (const float*)d_in[0];
    const float* gw = (const float*)d_in[1];
    const float* gb = (const float*)d_in[2];
    const float* w1 = (const float*)d_in[3];
    const float* b1 = (const float*)d_in[4];
    const float* w2 = (const float*)d_in[5];
    const float* b2 = (const float*)d_in[6];
    const int* topk = (const int*)d_in[7];
    float* out = (float*)d_out;

    char* ws = (char*)d_ws;
    size_t off = 0;
    int* counts = (int*)(ws + off);    off += 256;
    int* bucket = (int*)(ws + off);    off += (size_t)NEXP * T_TOK * 4;
    float* bw   = (float*)(ws + off);  off += (size_t)NEXP * T_TOK * 4;
    int* hdr    = (int*)(ws + off);    off += 4096;
    off = (off + 255) & ~(size_t)255;
    __bf16* xb  = (__bf16*)(ws + off); off += (size_t)T_TOK * DIM * 2;        // 8MB
    __bf16* w1t = (__bf16*)(ws + off); off += (size_t)NEXP * DIM * FDIM * 2;  // 64MB
    __bf16* w2t = (__bf16*)(ws + off); off += (size_t)NEXP * FDIM * DIM * 2;  // 64MB
    __bf16* H   = (__bf16*)(ws + off);                                        // 256MB

    hipMemsetAsync(counts, 0, 256, stream);
    hipMemsetAsync(out, 0, (size_t)out_size * 4, stream);

    moe_router<<<T_TOK, 64, 0, stream>>>(x, gw, gb, topk, counts, bucket, bw, xb);
    transpose_cvt<<<dim3(FDIM/64, DIM/64, NEXP), 256, 0, stream>>>(w1, w1t, DIM, FDIM);
    transpose_cvt<<<dim3(DIM/64, FDIM/64, NEXP), 256, 0, stream>>>(w2, w2t, FDIM, DIM);
    build_work<<<1, 64, 0, stream>>>(counts, hdr);

    moe_gemm1<<<1024, 256, 0, stream>>>(xb, w1t, b1, counts, bucket, hdr, H);
    moe_gemm2<<<512, 256, 0, stream>>>(H, w2t, b2, counts, bucket, bw, hdr, out);
}